// Round 8
// baseline (266.256 us; speedup 1.0000x reference)
//
#include <hip/hip_runtime.h>

// MoEConnectionProcessor — MI355X/gfx950 — Round 8: in-flight loads + occupancy.
// PROVEN: inputs f32, cat int32, output f32 (combined[N,64] ++ w[N,3]).
// vs r7: (1) agg loads batched 9/9/8 into regs (expose ~3 latencies, not 26),
//        (2) sa = sl+sf+sd (cat∈{0,1,2}), (3) LDS 33.3->23.0 KB (shared sb,
//        bf16 expert outs) + launch_bounds(256,6) -> 6 blocks/CU.

#define NCELL 19683
#define KNB 26
#define NGRP 1231  // ceil(NCELL/16)

typedef short bf16x8 __attribute__((ext_vector_type(8)));
typedef float f32x4 __attribute__((ext_vector_type(4)));

// fragment bases (1KB frags), frag index in matrix = nt*4 + kt
#define FB_L 0
#define FB_F1 16
#define FB_F2 48
#define FB_C1 64
#define FB_C2 96
#define FB_G1 112

__device__ __forceinline__ unsigned short f2b(float f) {
  unsigned u; __builtin_memcpy(&u, &f, 4);
  u += 0x7FFFu + ((u >> 16) & 1u);
  return (unsigned short)(u >> 16);
}
__device__ __forceinline__ float b2f(unsigned short h) {
  unsigned u = ((unsigned)h) << 16; float f; __builtin_memcpy(&f, &u, 4); return f;
}
__device__ __forceinline__ unsigned pack2(float x, float y) {
  return (unsigned)f2b(x) | ((unsigned)f2b(y) << 16);
}
__device__ __forceinline__ float tanh_fast(float x) {
  float e = __expf(2.0f * x);
  return 1.0f - 2.0f * __builtin_amdgcn_rcpf(e + 1.0f);  // exact at +/-inf
}

// ---------------- weight repack (120 frags, one per wave) ----------------
__global__ __launch_bounds__(256) void k_repack(
    const float* __restrict__ Wl, const float* __restrict__ Wf1,
    const float* __restrict__ Wf2, const float* __restrict__ Wc1,
    const float* __restrict__ Wc2, const float* __restrict__ Wg1,
    char* __restrict__ ws) {
  int frag = blockIdx.x * 4 + (threadIdx.x >> 6);
  int lane = threadIdx.x & 63;
  if (frag >= 120) return;
  const float* src; int Nd, lf;
  if (frag < 16)       { src = Wl;  Nd = 64;  lf = frag; }
  else if (frag < 48)  { src = Wf1; Nd = 128; lf = frag - 16; }
  else if (frag < 64)  { src = Wf2; Nd = 64;  lf = frag - 48; }
  else if (frag < 96)  { src = Wc1; Nd = 128; lf = frag - 64; }
  else if (frag < 112) { src = Wc2; Nd = 64;  lf = frag - 96; }
  else                 { src = Wg1; Nd = 32;  lf = frag - 112; }
  int nt = lf >> 2, kt = lf & 3;
  int n = nt * 16 + (lane & 15);
  int k0 = kt * 32 + (lane >> 4) * 8;
  unsigned short o[8] __attribute__((aligned(16)));
#pragma unroll
  for (int j = 0; j < 8; j++) o[j] = f2b(src[(k0 + j) * Nd + n]);
  *(uint4*)(ws + ((size_t)frag * 64 + lane) * 16) = *(const uint4*)o;
}

// ---------------- LDS fragment helpers (validated r3≡r4) ----------------
__device__ __forceinline__ void afrags2(const uint4* lo, const uint4* hi, int m, int q, bf16x8* a) {
#pragma unroll
  for (int kt = 0; kt < 4; kt++) {
    const uint4* b = (kt < 2) ? lo : hi;
    int ch = ((kt & 1) * 4 + q) ^ (m & 7);
    a[kt] = *(const bf16x8*)&b[m * 8 + ch];
  }
}
__device__ __forceinline__ void afragsS(const uint4* sb, int m, int q, bf16x8* a) {
#pragma unroll
  for (int kt = 0; kt < 4; kt++) {
    int ch = (kt * 4 + q) ^ m;
    a[kt] = *(const bf16x8*)&sb[m * 16 + ch];
  }
}
template <int NT>
__device__ __forceinline__ void gemmN(const bf16x8* __restrict__ wf, int fb, const bf16x8* a,
                                      int lane, f32x4* out) {
#pragma unroll
  for (int nt = 0; nt < NT; nt++) {
    f32x4 acc = {0.f, 0.f, 0.f, 0.f};
#pragma unroll
    for (int kt = 0; kt < 4; kt++) {
      bf16x8 b = wf[(fb + nt * 4 + kt) * 64 + lane];
      acc = __builtin_amdgcn_mfma_f32_16x16x32_bf16(a[kt], b, acc, 0, 0, 0);
    }
    out[nt] = acc;
  }
}
__device__ __forceinline__ void store_sb(uint4* sb, int cell, int feat, float v) {
  ((unsigned short*)&sb[cell * 16 + ((feat >> 3) ^ cell)])[feat & 7] = f2b(v);
}
__device__ __forceinline__ void store_xb(uint4* xb, int cell, int feat, float v) {
  ((unsigned short*)&xb[cell * 8 + ((feat >> 3) ^ (cell & 7))])[feat & 7] = f2b(v);
}

// ---------------- fused main kernel ----------------
__global__ __launch_bounds__(256, 6) void k_main(
    const float* __restrict__ curp, const float* __restrict__ nbp, const int* __restrict__ catp,
    const float* __restrict__ bl_, const float* __restrict__ bf1_, const float* __restrict__ bf2_,
    const float* __restrict__ bc1_, const float* __restrict__ bc2_, const float* __restrict__ bg1_,
    const float* __restrict__ Wg2, const float* __restrict__ bg2_,
    const char* __restrict__ ws, float* __restrict__ outp) {
  __shared__ uint4 smem[1440];  // 23040 B
  uint4* curb = smem;           // 128: 16 cells x 64 bf16, swizzled
  uint4* mlb  = smem + 128;     // 128
  uint4* mfb  = smem + 256;     // 128
  uint4* mdb  = smem + 384;     // 128
  uint4* actb = smem + 512;     // 128
  uint4* xb   = smem + 640;     // 128
  uint4* sbS  = smem + 768;     // 256: 16 x 128 bf16 (w1's h, THEN CNF h — lifetimes split by barrier)
  unsigned short* outLh = (unsigned short*)(smem + 1024);  // 16 x 64 bf16
  unsigned short* outFh = (unsigned short*)(smem + 1152);
  unsigned short* outDh = (unsigned short*)(smem + 1280);
  float4* flagsb = (float4*)(smem + 1408);  // 16
  float4* wvalsb = (float4*)(smem + 1424);  // 16

  int tid = threadIdx.x, lane = tid & 63, wv = tid >> 6;
  int g = blockIdx.x;

  // ---- phase A: aggregation (each wave: 4 cells; lane: cell=lane>>4, 4 feats) ----
  {
    int cq = lane >> 4, fq = lane & 15;
    int cellLoc = wv * 4 + cq;
    int cell = min(g * 16 + cellLoc, NCELL - 1);
    int c0 = catp[cell * KNB + fq];
    int c1 = (fq < KNB - 16) ? catp[cell * KNB + 16 + fq] : -1;
    unsigned long long B0a = __ballot(c0 == 0), B1a = __ballot(c0 == 1), B2a = __ballot(c0 == 2);
    unsigned long long B0b = __ballot(c1 == 0), B1b = __ballot(c1 == 1), B2b = __ballot(c1 == 2);
    int sh = cq * 16;
    unsigned m0 = (unsigned)((B0a >> sh) & 0xFFFFull) | ((unsigned)((B0b >> sh) & 0x3FFull) << 16);
    unsigned m1 = (unsigned)((B1a >> sh) & 0xFFFFull) | ((unsigned)((B1b >> sh) & 0x3FFull) << 16);
    unsigned m2 = (unsigned)((B2a >> sh) & 0xFFFFull) | ((unsigned)((B2b >> sh) & 0x3FFull) << 16);
    float cl = (float)__popc(m0), cf = (float)__popc(m1), cd = (float)__popc(m2);
    float sl[4] = {0, 0, 0, 0}, sf[4] = {0, 0, 0, 0}, sd[4] = {0, 0, 0, 0};
    const float* nbc = nbp + (size_t)cell * (KNB * 64) + fq * 4;
    // batched loads: expose 3 memory latencies instead of 26
#pragma unroll
    for (int b = 0; b < 3; b++) {
      const int k0 = b * 9;
      const int kn = (b == 2) ? 8 : 9;
      float4 v[9];
#pragma unroll
      for (int k = 0; k < 9; k++)
        if (k < kn) v[k] = *(const float4*)(nbc + (k0 + k) * 64);
#pragma unroll
      for (int k = 0; k < 9; k++) {
        if (k >= kn) break;
        int kk = k0 + k;
        float b0 = (float)((m0 >> kk) & 1u);
        float b1 = (float)((m1 >> kk) & 1u);
        float b2 = (float)((m2 >> kk) & 1u);
        sl[0] += b0 * v[k].x; sl[1] += b0 * v[k].y; sl[2] += b0 * v[k].z; sl[3] += b0 * v[k].w;
        sf[0] += b1 * v[k].x; sf[1] += b1 * v[k].y; sf[2] += b1 * v[k].z; sf[3] += b1 * v[k].w;
        sd[0] += b2 * v[k].x; sd[1] += b2 * v[k].y; sd[2] += b2 * v[k].z; sd[3] += b2 * v[k].w;
      }
    }
    float rl = 1.0f / fmaxf(cl, 1.0f);
    float rf = 1.0f / fmaxf(cf, 1.0f);
    float rd = 1.0f / fmaxf(cd, 1.0f);
    const float r26 = 1.0f / 26.0f;
    int ch = (fq >> 1) ^ (cellLoc & 7);
    int sub = fq & 1;
    ((uint2*)&mlb[cellLoc * 8 + ch])[sub] =
        make_uint2(pack2(sl[0] * rl, sl[1] * rl), pack2(sl[2] * rl, sl[3] * rl));
    ((uint2*)&mfb[cellLoc * 8 + ch])[sub] =
        make_uint2(pack2(sf[0] * rf, sf[1] * rf), pack2(sf[2] * rf, sf[3] * rf));
    ((uint2*)&mdb[cellLoc * 8 + ch])[sub] =
        make_uint2(pack2(sd[0] * rd, sd[1] * rd), pack2(sd[2] * rd, sd[3] * rd));
    ((uint2*)&actb[cellLoc * 8 + ch])[sub] =
        make_uint2(pack2((sl[0] + sf[0] + sd[0]) * r26, (sl[1] + sf[1] + sd[1]) * r26),
                   pack2((sl[2] + sf[2] + sd[2]) * r26, (sl[3] + sf[3] + sd[3]) * r26));
    if (fq == 0)
      flagsb[cellLoc] = make_float4(cl > 0.f ? 1.f : 0.f, cf > 0.f ? 1.f : 0.f,
                                    cd > 0.f ? 1.f : 0.f, 0.f);
  }
  // cur -> LDS bf16 (threads 0..127)
  if (tid < 128) {
    int cellLoc = tid >> 3, c = tid & 7;
    int cell = min(g * 16 + cellLoc, NCELL - 1);
    const float4* cp = (const float4*)(curp + (size_t)cell * 64) + c * 2;
    float4 A = cp[0], B = cp[1];
    uint4 o;
    o.x = pack2(A.x, A.y); o.y = pack2(A.z, A.w);
    o.z = pack2(B.x, B.y); o.w = pack2(B.z, B.w);
    curb[cellLoc * 8 + (c ^ (cellLoc & 7))] = o;
  }

  int m = lane & 15, q = lane >> 4;
  const bf16x8* wf = (const bf16x8*)ws;
  bf16x8 a4[4];
  float xr[2][4];

  // CNF x init from f32 cur (global; no LDS dependency)
  if (wv >= 2) {
    int ntb = (wv - 2) * 2;
#pragma unroll
    for (int j = 0; j < 2; j++)
#pragma unroll
      for (int r = 0; r < 4; r++) {
        int cell = min(g * 16 + q * 4 + r, NCELL - 1);
        xr[j][r] = curp[(size_t)cell * 64 + (ntb + j) * 16 + m];
      }
  }
  __syncthreads();  // (1) staging complete

  if (wv == 0) {
    // ---- local expert ----
    afrags2(curb, mlb, m, q, a4);
    f32x4 ol[4];
    gemmN<4>(wf, FB_L, a4, lane, ol);
#pragma unroll
    for (int nt = 0; nt < 4; nt++) {
      float bb = bl_[nt * 16 + m];
#pragma unroll
      for (int r = 0; r < 4; r++)
        outLh[(q * 4 + r) * 64 + nt * 16 + m] = f2b(tanh_fast(ol[nt][r] + bb));
    }
    // ---- gating ----
    afrags2(curb, actb, m, q, a4);
    f32x4 gh[2];
    gemmN<2>(wf, FB_G1, a4, lane, gh);
#pragma unroll
    for (int nt = 0; nt < 2; nt++) {
      float bb = bg1_[nt * 16 + m];
#pragma unroll
      for (int r = 0; r < 4; r++) gh[nt][r] = tanh_fast(gh[nt][r] + bb);
    }
    float w2v[2][3];
#pragma unroll
    for (int nt = 0; nt < 2; nt++)
#pragma unroll
      for (int t = 0; t < 3; t++) w2v[nt][t] = Wg2[(nt * 16 + m) * 3 + t];
    float bg2v[3] = {bg2_[0], bg2_[1], bg2_[2]};
#pragma unroll
    for (int r = 0; r < 4; r++) {
      float gv[3];
#pragma unroll
      for (int t = 0; t < 3; t++) {
        float p = gh[0][r] * w2v[0][t] + gh[1][r] * w2v[1][t];
        p += __shfl_xor(p, 1); p += __shfl_xor(p, 2); p += __shfl_xor(p, 4); p += __shfl_xor(p, 8);
        gv[t] = p + bg2v[t];
      }
      float mx = fmaxf(gv[0], fmaxf(gv[1], gv[2]));
      float e0 = __expf(gv[0] - mx), e1 = __expf(gv[1] - mx), e2 = __expf(gv[2] - mx);
      float rs = __builtin_amdgcn_rcpf(e0 + e1 + e2);
      int cellLoc = q * 4 + r;
      int cell = g * 16 + cellLoc;
      if (m == 0) wvalsb[cellLoc] = make_float4(e0 * rs, e1 * rs, e2 * rs, 0.f);
      if (cell < NCELL && m < 3) {
        float wsel = (m == 0) ? e0 * rs : (m == 1) ? e1 * rs : e2 * rs;
        outp[(size_t)NCELL * 64 + cell * 3 + m] = wsel;
      }
    }
  } else if (wv == 1) {
    // ---- functional expert (uses sbS; done before barrier (2) frees it for CNF) ----
    afrags2(curb, mfb, m, q, a4);
    f32x4 h8[8];
    gemmN<8>(wf, FB_F1, a4, lane, h8);
#pragma unroll
    for (int nt = 0; nt < 8; nt++) {
      float bb = bf1_[nt * 16 + m];
#pragma unroll
      for (int r = 0; r < 4; r++)
        store_sb(sbS, q * 4 + r, nt * 16 + m, tanh_fast(h8[nt][r] + bb));
    }
    afragsS(sbS, m, q, a4);
    f32x4 of4[4];
    gemmN<4>(wf, FB_F2, a4, lane, of4);
#pragma unroll
    for (int nt = 0; nt < 4; nt++) {
      float bb = bf2_[nt * 16 + m];
#pragma unroll
      for (int r = 0; r < 4; r++)
        outFh[(q * 4 + r) * 64 + nt * 16 + m] = f2b(tanh_fast(of4[nt][r] + bb));
    }
  } else {
    // ---- CNF: write x init to xb (disjoint feat halves) ----
    int ntb = (wv - 2) * 2;
#pragma unroll
    for (int j = 0; j < 2; j++)
#pragma unroll
      for (int r = 0; r < 4; r++) store_xb(xb, q * 4 + r, (ntb + j) * 16 + m, xr[j][r]);
  }

  // ---- CNF steps: w2 (h cols 0..63, dx 0..31) + w3 (h 64..127, dx 32..63) ----
  for (int step = 0; step < 3; step++) {
    __syncthreads();  // (2,4,6) xb ready; sbS free (w1 finished its reads before this)
    if (wv >= 2) {
      int hb = (wv - 2) * 4;
      afrags2(xb, mdb, m, q, a4);
      f32x4 v4[4];
      gemmN<4>(wf, FB_C1 + hb * 4, a4, lane, v4);
#pragma unroll
      for (int j = 0; j < 4; j++) {
        int nt = hb + j;
        float bb = bc1_[nt * 16 + m];
#pragma unroll
        for (int r = 0; r < 4; r++)
          store_sb(sbS, q * 4 + r, nt * 16 + m, tanh_fast(v4[j][r] + bb));
      }
    }
    __syncthreads();  // (3,5,7) h ready
    if (wv >= 2) {
      int ntb = (wv - 2) * 2;
      afragsS(sbS, m, q, a4);
      f32x4 dx2[2];
      gemmN<2>(wf, FB_C2 + ntb * 4, a4, lane, dx2);
#pragma unroll
      for (int j = 0; j < 2; j++) {
        int nt = ntb + j;
        float bb = bc2_[nt * 16 + m];
#pragma unroll
        for (int r = 0; r < 4; r++) {
          xr[j][r] += (1.0f / 3.0f) * tanh_fast(dx2[j][r] + bb);
          if (step < 2) store_xb(xb, q * 4 + r, nt * 16 + m, xr[j][r]);
          else outDh[(q * 4 + r) * 64 + nt * 16 + m] = f2b(xr[j][r]);
        }
      }
    }
  }
  __syncthreads();  // (8) all expert outputs in LDS

  // ---- cooperative combine + coalesced float4 store ----
  {
    int cellLoc = tid >> 4, fi = tid & 15;
    uint2 ul = ((const uint2*)outLh)[cellLoc * 16 + fi];
    uint2 uf = ((const uint2*)outFh)[cellLoc * 16 + fi];
    uint2 ud = ((const uint2*)outDh)[cellLoc * 16 + fi];
    float4 fl = flagsb[cellLoc];
    float4 wv4 = wvalsb[cellLoc];
    float a0 = wv4.x * fl.x, a1 = wv4.y * fl.y, a2 = wv4.z * fl.z;
    int cell = g * 16 + cellLoc;
    if (cell < NCELL) {
      float4 res;
      res.x = a0 * b2f((unsigned short)ul.x) + a1 * b2f((unsigned short)uf.x) +
              a2 * b2f((unsigned short)ud.x);
      res.y = a0 * b2f((unsigned short)(ul.x >> 16)) + a1 * b2f((unsigned short)(uf.x >> 16)) +
              a2 * b2f((unsigned short)(ud.x >> 16));
      res.z = a0 * b2f((unsigned short)ul.y) + a1 * b2f((unsigned short)uf.y) +
              a2 * b2f((unsigned short)ud.y);
      res.w = a0 * b2f((unsigned short)(ul.y >> 16)) + a1 * b2f((unsigned short)(uf.y >> 16)) +
              a2 * b2f((unsigned short)(ud.y >> 16));
      ((float4*)(outp + (size_t)cell * 64))[fi] = res;
    }
  }
}

extern "C" void kernel_launch(void* const* d_in, const int* in_sizes, int n_in,
                              void* d_out, int out_size, void* d_ws, size_t ws_size,
                              hipStream_t stream) {
  const float* cur = (const float*)d_in[0];
  const float* nb  = (const float*)d_in[1];
  const int* cat   = (const int*)d_in[2];
  const float* Wl  = (const float*)d_in[3];
  const float* bl  = (const float*)d_in[4];
  const float* Wf1 = (const float*)d_in[5];
  const float* bf1 = (const float*)d_in[6];
  const float* Wf2 = (const float*)d_in[7];
  const float* bf2 = (const float*)d_in[8];
  const float* Wc1 = (const float*)d_in[9];
  const float* bc1 = (const float*)d_in[10];
  const float* Wc2 = (const float*)d_in[11];
  const float* bc2 = (const float*)d_in[12];
  const float* Wg1 = (const float*)d_in[13];
  const float* bg1 = (const float*)d_in[14];
  const float* Wg2 = (const float*)d_in[15];
  const float* bg2 = (const float*)d_in[16];
  char* ws = (char*)d_ws;
  float* outp = (float*)d_out;

  k_repack<<<30, 256, 0, stream>>>(Wl, Wf1, Wf2, Wc1, Wc2, Wg1, ws);
  k_main<<<NGRP, 256, 0, stream>>>(cur, nb, cat, bl, bf1, bf2, bc1, bc2, bg1, Wg2, bg2,
                                   (const char*)ws, outp);
}